// Round 1
// baseline (245.236 us; speedup 1.0000x reference)
//
#include <hip/hip_runtime.h>
#include <hip/hip_bf16.h>

typedef __bf16 bf16x8 __attribute__((ext_vector_type(8)));
typedef __bf16 bf16x2 __attribute__((ext_vector_type(2)));
typedef float  f32x4  __attribute__((ext_vector_type(4)));

#define T_SEQ 2048
#define D_HEAD 64
#define BH_N 32
#define TQ 64
#define TK 64
#define KSTR 72   // padded LDS row stride in bf16 elements (144 B = 36 dwords; breaks 32-bank aliasing)

__global__ __launch_bounds__(256) void attn_kernel(
    const float* __restrict__ q, const float* __restrict__ k,
    const float* __restrict__ v, const int* __restrict__ mask,
    float* __restrict__ out)
{
    const int bh   = blockIdx.x;   // 0..31  (b*H+h)
    const int qt   = blockIdx.y;   // 0..31  (q tile of 64 rows)
    const int tid  = threadIdx.x;
    const int wave = tid >> 6;
    const int lane = tid & 63;
    const int g    = lane >> 4;    // quad-group 0..3
    const int ln   = lane & 15;

    __shared__ __align__(16) __bf16 Kl[TK * KSTR];          // K tile, row-major [key][d]
    __shared__ __align__(16) __bf16 Vt[D_HEAD * KSTR];      // V tile, transposed [d][key]
    __shared__ __align__(16) __bf16 Pl[4][16 * KSTR];       // per-wave P tile [qrow][key]

    // ---- Q fragments (A-layout: m = ln, k = kc*32 + g*8 + j), persistent in regs
    const int qrow_frag = qt * TQ + wave * 16 + ln;
    const float* qp = q + ((size_t)bh * T_SEQ + qrow_frag) * D_HEAD;
    bf16x8 qf[2];
#pragma unroll
    for (int kc = 0; kc < 2; ++kc) {
        const float4 f0 = *(const float4*)(qp + kc * 32 + g * 8);
        const float4 f1 = *(const float4*)(qp + kc * 32 + g * 8 + 4);
        qf[kc][0] = (__bf16)f0.x; qf[kc][1] = (__bf16)f0.y;
        qf[kc][2] = (__bf16)f0.z; qf[kc][3] = (__bf16)f0.w;
        qf[kc][4] = (__bf16)f1.x; qf[kc][5] = (__bf16)f1.y;
        qf[kc][6] = (__bf16)f1.z; qf[kc][7] = (__bf16)f1.w;
    }

    f32x4 o[4];
#pragma unroll
    for (int nt = 0; nt < 4; ++nt) o[nt] = (f32x4){0.f, 0.f, 0.f, 0.f};
    float m_i[4], l_i[4];
#pragma unroll
    for (int r = 0; r < 4; ++r) { m_i[r] = -1e30f; l_i[r] = 0.f; }

    const float scale = 0.125f;            // D^-0.5
    const int q0 = qt * TQ + wave * 16 + g * 4;   // first of this lane's 4 C-layout rows

    // per-row mask base pointers (col = kt*64 + nt*16 + ln)
    const int* mrow[4];
#pragma unroll
    for (int r = 0; r < 4; ++r) mrow[r] = mask + (size_t)(q0 + r) * T_SEQ + ln;

    // staging geometry
    const int krow = tid >> 2, kpart = tid & 3;            // K: 16 contiguous floats each
    const int vj0 = (tid & 31) * 2, vd0 = (tid >> 5) * 8;  // V: 2 rows x 8 d's

    for (int kt = 0; kt < T_SEQ / TK; ++kt) {
        __syncthreads();   // previous tile's LDS reads complete before overwrite

        // ---- stage K tile (row-major bf16)
        {
            const float* kp = k + ((size_t)bh * T_SEQ + kt * TK + krow) * D_HEAD + kpart * 16;
            const float4 a0 = *(const float4*)(kp);
            const float4 a1 = *(const float4*)(kp + 4);
            const float4 a2 = *(const float4*)(kp + 8);
            const float4 a3 = *(const float4*)(kp + 12);
            bf16x8 w0, w1;
            w0[0]=(__bf16)a0.x; w0[1]=(__bf16)a0.y; w0[2]=(__bf16)a0.z; w0[3]=(__bf16)a0.w;
            w0[4]=(__bf16)a1.x; w0[5]=(__bf16)a1.y; w0[6]=(__bf16)a1.z; w0[7]=(__bf16)a1.w;
            w1[0]=(__bf16)a2.x; w1[1]=(__bf16)a2.y; w1[2]=(__bf16)a2.z; w1[3]=(__bf16)a2.w;
            w1[4]=(__bf16)a3.x; w1[5]=(__bf16)a3.y; w1[6]=(__bf16)a3.z; w1[7]=(__bf16)a3.w;
            *(bf16x8*)(&Kl[krow * KSTR + kpart * 16])     = w0;
            *(bf16x8*)(&Kl[krow * KSTR + kpart * 16 + 8]) = w1;
        }
        // ---- stage V transposed: VT[d][key], packed pair-of-keys dword writes
        {
            const float* vp = v + ((size_t)bh * T_SEQ + kt * TK + vj0) * D_HEAD + vd0;
            const float4 r00 = *(const float4*)(vp);
            const float4 r01 = *(const float4*)(vp + 4);
            const float4 r10 = *(const float4*)(vp + D_HEAD);
            const float4 r11 = *(const float4*)(vp + D_HEAD + 4);
            float e0[8] = {r00.x, r00.y, r00.z, r00.w, r01.x, r01.y, r01.z, r01.w};
            float e1[8] = {r10.x, r10.y, r10.z, r10.w, r11.x, r11.y, r11.z, r11.w};
#pragma unroll
            for (int i = 0; i < 8; ++i) {
                bf16x2 pr = { (__bf16)e0[i], (__bf16)e1[i] };
                *(bf16x2*)(&Vt[(vd0 + i) * KSTR + vj0]) = pr;
            }
        }
        __syncthreads();

        // ---- S = Q K^T  (8 MFMAs; C layout: row = g*4+r, col = nt*16+ln)
        f32x4 s[4];
#pragma unroll
        for (int nt = 0; nt < 4; ++nt) {
            const bf16x8 kf0 = *(const bf16x8*)(&Kl[(nt * 16 + ln) * KSTR + g * 8]);
            const bf16x8 kf1 = *(const bf16x8*)(&Kl[(nt * 16 + ln) * KSTR + 32 + g * 8]);
            f32x4 c = (f32x4){0.f, 0.f, 0.f, 0.f};
            c = __builtin_amdgcn_mfma_f32_16x16x32_bf16(qf[0], kf0, c, 0, 0, 0);
            c = __builtin_amdgcn_mfma_f32_16x16x32_bf16(qf[1], kf1, c, 0, 0, 0);
            s[nt] = c;
        }

        // ---- scale + mask (masked -> -1e30)
#pragma unroll
        for (int nt = 0; nt < 4; ++nt) {
#pragma unroll
            for (int r = 0; r < 4; ++r) {
                const float sv = s[nt][r] * scale;
                const int mk = mrow[r][kt * TK + nt * 16];
                s[nt][r] = mk ? -1e30f : sv;
            }
        }

        // ---- online softmax: row max over 64 keys (4 nt-tiles x 16 lanes)
        float tm[4];
#pragma unroll
        for (int r = 0; r < 4; ++r)
            tm[r] = fmaxf(fmaxf(s[0][r], s[1][r]), fmaxf(s[2][r], s[3][r]));
#pragma unroll
        for (int off = 1; off < 16; off <<= 1) {
#pragma unroll
            for (int r = 0; r < 4; ++r)
                tm[r] = fmaxf(tm[r], __shfl_xor(tm[r], off, 64));
        }

        float alpha[4];
#pragma unroll
        for (int r = 0; r < 4; ++r) {
            const float mn = fmaxf(m_i[r], tm[r]);
            alpha[r] = __expf(m_i[r] - mn);
            m_i[r] = mn;
        }
#pragma unroll
        for (int nt = 0; nt < 4; ++nt)
#pragma unroll
            for (int r = 0; r < 4; ++r) o[nt][r] *= alpha[r];

        // ---- p = exp(s-m) (0 if masked), write P to per-wave LDS, partial row-sum
        float rs[4] = {0.f, 0.f, 0.f, 0.f};
#pragma unroll
        for (int nt = 0; nt < 4; ++nt) {
#pragma unroll
            for (int r = 0; r < 4; ++r) {
                const float sv = s[nt][r];
                const float p = (sv < -1e29f) ? 0.f : __expf(sv - m_i[r]);
                rs[r] += p;
                Pl[wave][(g * 4 + r) * KSTR + nt * 16 + ln] = (__bf16)p;
            }
        }
#pragma unroll
        for (int off = 1; off < 16; off <<= 1) {
#pragma unroll
            for (int r = 0; r < 4; ++r) rs[r] += __shfl_xor(rs[r], off, 64);
        }
#pragma unroll
        for (int r = 0; r < 4; ++r) l_i[r] = l_i[r] * alpha[r] + rs[r];

        // ---- PV: P in A-layout (wave-private LDS region; DS in-order per wave)
        const bf16x8 pf0 = *(const bf16x8*)(&Pl[wave][ln * KSTR + g * 8]);
        const bf16x8 pf1 = *(const bf16x8*)(&Pl[wave][ln * KSTR + 32 + g * 8]);
#pragma unroll
        for (int nt = 0; nt < 4; ++nt) {
            const bf16x8 vf0 = *(const bf16x8*)(&Vt[(nt * 16 + ln) * KSTR + g * 8]);
            const bf16x8 vf1 = *(const bf16x8*)(&Vt[(nt * 16 + ln) * KSTR + 32 + g * 8]);
            o[nt] = __builtin_amdgcn_mfma_f32_16x16x32_bf16(pf0, vf0, o[nt], 0, 0, 0);
            o[nt] = __builtin_amdgcn_mfma_f32_16x16x32_bf16(pf1, vf1, o[nt], 0, 0, 0);
        }
    }

    // ---- epilogue: normalize, fully-masked rows -> 0
#pragma unroll
    for (int r = 0; r < 4; ++r) {
        const float inv = (l_i[r] > 0.f) ? (1.0f / l_i[r]) : 0.f;
        float* op = out + ((size_t)bh * T_SEQ + q0 + r) * D_HEAD + ln;
#pragma unroll
        for (int nt = 0; nt < 4; ++nt)
            op[nt * 16] = o[nt][r] * inv;
    }
}

extern "C" void kernel_launch(void* const* d_in, const int* in_sizes, int n_in,
                              void* d_out, int out_size, void* d_ws, size_t ws_size,
                              hipStream_t stream) {
    const float* q    = (const float*)d_in[0];
    const float* k    = (const float*)d_in[1];
    const float* v    = (const float*)d_in[2];
    const int*   mask = (const int*)d_in[3];
    float*       out  = (float*)d_out;
    dim3 grid(BH_N, T_SEQ / TQ);   // x = b*H+h (fast) so concurrent blocks share mask rows
    attn_kernel<<<grid, 256, 0, stream>>>(q, k, v, mask, out);
}

// Round 2
// 193.825 us; speedup vs baseline: 1.2652x; 1.2652x over previous
//
#include <hip/hip_runtime.h>
#include <hip/hip_bf16.h>

typedef __bf16 bf16x8 __attribute__((ext_vector_type(8)));
typedef __bf16 bf16x4 __attribute__((ext_vector_type(4)));
typedef __bf16 bf16x2 __attribute__((ext_vector_type(2)));
typedef float  f32x4  __attribute__((ext_vector_type(4)));

#define T_SEQ 2048
#define D_HEAD 64
#define BH_N 32
#define TQ 128
#define TK 64
#define SCALE_LOG2 0.18033688011112042f   // 0.125 * log2(e)

// workspace layout (bytes)
#define WS_KBF 0u
#define WS_VTB (8u<<20)
#define WS_MB  (16u<<20)
#define WS_NEED ((size_t)(16u<<20) + (size_t)T_SEQ*32*8)

// ---------------- pre-pass kernels ----------------

__global__ void cvt_k(const float* __restrict__ k, __bf16* __restrict__ kb) {
    const int i = (blockIdx.x * 256 + threadIdx.x) * 8;
    const float4 a = *(const float4*)(k + i);
    const float4 b = *(const float4*)(k + i + 4);
    bf16x8 w;
    w[0]=(__bf16)a.x; w[1]=(__bf16)a.y; w[2]=(__bf16)a.z; w[3]=(__bf16)a.w;
    w[4]=(__bf16)b.x; w[5]=(__bf16)b.y; w[6]=(__bf16)b.z; w[7]=(__bf16)b.w;
    *(bf16x8*)(kb + i) = w;
}

__global__ void vtrans(const float* __restrict__ v, __bf16* __restrict__ vt) {
    __shared__ __bf16 t[64][72];
    const int bh = blockIdx.y, tt = blockIdx.x, tid = threadIdx.x;
    const int tr = tid >> 4, c4 = (tid & 15) * 4;
    const float* src = v + ((size_t)bh * T_SEQ + tt * 64) * D_HEAD;
#pragma unroll
    for (int p = 0; p < 4; ++p) {
        const int row = p * 16 + tr;
        const float4 f = *(const float4*)(src + row * D_HEAD + c4);
        t[c4+0][row] = (__bf16)f.x; t[c4+1][row] = (__bf16)f.y;
        t[c4+2][row] = (__bf16)f.z; t[c4+3][row] = (__bf16)f.w;
    }
    __syncthreads();
    const int d = tid >> 2, seg = tid & 3;
    const bf16x8 a = *(bf16x8*)&t[d][seg*16];
    const bf16x8 b = *(bf16x8*)&t[d][seg*16+8];
    __bf16* dst = vt + ((size_t)bh * D_HEAD + d) * T_SEQ + tt * 64 + seg * 16;
    *(bf16x8*)dst = a; *(bf16x8*)(dst + 8) = b;
}

__global__ void mpack(const int* __restrict__ m, unsigned long long* __restrict__ mb) {
    const int i = blockIdx.x * 256 + threadIdx.x;
    const unsigned long long b = __ballot(m[i] != 0);
    if ((threadIdx.x & 63) == 0) mb[i >> 6] = b;
}

// ---------------- main kernel ----------------
// S^T formulation: A = K-frag (LDS), B = Q-frag (regs) -> C[m=key][n=q].
// No running max (log2-domain scores bounded); mask via u64 bitwords.

__global__ __launch_bounds__(256) void attn_main(
    const float* __restrict__ q, const __bf16* __restrict__ kb,
    const __bf16* __restrict__ vt, const unsigned long long* __restrict__ mb,
    float* __restrict__ out)
{
    const int qt = blockIdx.x, bh = blockIdx.y;
    const int tid = threadIdx.x, wave = tid >> 6, lane = tid & 63;
    const int g = lane >> 4, ln = lane & 15;

    __shared__ __align__(16) __bf16 Kl[TK * 64];       // swizzled, stride 128B
    __shared__ __align__(16) __bf16 Vl[D_HEAD * 64];   // swizzled, stride 128B
    __shared__ __align__(16) __bf16 Pl[4][32 * 72];    // per-wave, padded

    const int qw = qt * TQ + wave * 32;

    // Q B-frags (scaled into log2 domain); content Q[q=ln][d=g*8+j+32kc]
    bf16x8 qf[2][2];
#pragma unroll
    for (int qs = 0; qs < 2; ++qs) {
        const float* qp = q + ((size_t)bh * T_SEQ + qw + qs*16 + ln) * D_HEAD + g * 8;
#pragma unroll
        for (int kc = 0; kc < 2; ++kc) {
            const float4 f0 = *(const float4*)(qp + kc * 32);
            const float4 f1 = *(const float4*)(qp + kc * 32 + 4);
            qf[qs][kc][0]=(__bf16)(f0.x*SCALE_LOG2); qf[qs][kc][1]=(__bf16)(f0.y*SCALE_LOG2);
            qf[qs][kc][2]=(__bf16)(f0.z*SCALE_LOG2); qf[qs][kc][3]=(__bf16)(f0.w*SCALE_LOG2);
            qf[qs][kc][4]=(__bf16)(f1.x*SCALE_LOG2); qf[qs][kc][5]=(__bf16)(f1.y*SCALE_LOG2);
            qf[qs][kc][6]=(__bf16)(f1.z*SCALE_LOG2); qf[qs][kc][7]=(__bf16)(f1.w*SCALE_LOG2);
        }
    }

    f32x4 o[2][4];
#pragma unroll
    for (int qs = 0; qs < 2; ++qs)
#pragma unroll
        for (int mt = 0; mt < 4; ++mt) o[qs][mt] = (f32x4){0.f,0.f,0.f,0.f};
    float lsum[2] = {0.f, 0.f};

    // LDS frag read base (bytes): row=nt*16+ln (stride 128B), chunk g ^ (ln&7)
    const int rb = ln * 128 + ((g ^ (ln & 7)) * 16);
    // staging: thread -> row kr, 32B at col seg*16; chunks 2seg, 2seg+1 swizzled
    const int kr = tid >> 2, seg = tid & 3;
    const int sw = kr * 128 + (((2*seg) ^ (kr & 7)) * 16);
    const __bf16* kbase = kb + (size_t)bh * T_SEQ * D_HEAD;
    const __bf16* vbase = vt + (size_t)bh * D_HEAD * T_SEQ;
    const unsigned long long* mrow0 = mb + (size_t)(qw + ln) * 32;
    const unsigned long long* mrow1 = mb + (size_t)(qw + 16 + ln) * 32;

    char* KlB = (char*)Kl;
    char* VlB = (char*)Vl;

    for (int kt = 0; kt < T_SEQ / TK; ++kt) {
        const unsigned long long w0 = mrow0[kt], w1 = mrow1[kt];
        __syncthreads();   // previous tile's LDS reads done
        {
            const __bf16* kp = kbase + (size_t)(kt * TK + kr) * D_HEAD + seg * 16;
            const bf16x8 k0 = *(const bf16x8*)kp;
            const bf16x8 k1 = *(const bf16x8*)(kp + 8);
            *(bf16x8*)(KlB + sw)        = k0;
            *(bf16x8*)(KlB + (sw ^ 16)) = k1;
            const __bf16* vp = vbase + (size_t)kr * T_SEQ + kt * TK + seg * 16;
            const bf16x8 v0 = *(const bf16x8*)vp;
            const bf16x8 v1 = *(const bf16x8*)(vp + 8);
            *(bf16x8*)(VlB + sw)        = v0;
            *(bf16x8*)(VlB + (sw ^ 16)) = v1;
        }
        __syncthreads();

        const unsigned long long ws0 = w0 >> (g * 4), ws1 = w1 >> (g * 4);
        const unsigned int mlo[2] = {(unsigned)ws0, (unsigned)ws1};
        const unsigned int mhi[2] = {(unsigned)(ws0 >> 32), (unsigned)(ws1 >> 32)};

        // ---- S^T = K . Q^T, exp2, mask, P write (packed b64)
#pragma unroll
        for (int nt = 0; nt < 4; ++nt) {
            const bf16x8 a0 = *(const bf16x8*)(KlB + nt * 2048 + rb);
            const bf16x8 a1 = *(const bf16x8*)(KlB + nt * 2048 + (rb ^ 64));
#pragma unroll
            for (int qs = 0; qs < 2; ++qs) {
                f32x4 c = (f32x4){0.f,0.f,0.f,0.f};
                c = __builtin_amdgcn_mfma_f32_16x16x32_bf16(a0, qf[qs][0], c, 0,0,0);
                c = __builtin_amdgcn_mfma_f32_16x16x32_bf16(a1, qf[qs][1], c, 0,0,0);
                const unsigned int bits = (nt < 2) ? mlo[qs] : mhi[qs];
                float p[4];
#pragma unroll
                for (int r = 0; r < 4; ++r) {
                    const float e = exp2f(c[r]);
                    p[r] = (bits & (1u << ((nt & 1) * 16 + r))) ? 0.f : e;
                }
                lsum[qs] += (p[0] + p[1]) + (p[2] + p[3]);
                bf16x4 pk = { (__bf16)p[0], (__bf16)p[1], (__bf16)p[2], (__bf16)p[3] };
                *(bf16x4*)(&Pl[wave][(qs*16 + ln) * 72 + nt * 16 + g * 4]) = pk;
            }
        }

        // ---- PV: A = V^T (LDS), B = P^T (== P[q=ln][key] rows, b128)
        bf16x8 pf[2][2];
#pragma unroll
        for (int qs = 0; qs < 2; ++qs)
#pragma unroll
            for (int kc = 0; kc < 2; ++kc)
                pf[qs][kc] = *(const bf16x8*)(&Pl[wave][(qs*16 + ln) * 72 + kc * 32 + g * 8]);
#pragma unroll
        for (int mt = 0; mt < 4; ++mt) {
            const bf16x8 a0 = *(const bf16x8*)(VlB + mt * 2048 + rb);
            const bf16x8 a1 = *(const bf16x8*)(VlB + mt * 2048 + (rb ^ 64));
#pragma unroll
            for (int qs = 0; qs < 2; ++qs) {
                o[qs][mt] = __builtin_amdgcn_mfma_f32_16x16x32_bf16(a0, pf[qs][0], o[qs][mt], 0,0,0);
                o[qs][mt] = __builtin_amdgcn_mfma_f32_16x16x32_bf16(a1, pf[qs][1], o[qs][mt], 0,0,0);
            }
        }
    }

    // ---- epilogue: O^T frag rows = d = mt*16+g*4+r, col = q = qw+qs*16+ln
#pragma unroll
    for (int qs = 0; qs < 2; ++qs) {
        float l = lsum[qs];
        l += __shfl_xor(l, 16, 64);
        l += __shfl_xor(l, 32, 64);
        const float inv = (l > 0.f) ? (1.f / l) : 0.f;
        float* op = out + ((size_t)bh * T_SEQ + qw + qs*16 + ln) * D_HEAD + g * 4;
#pragma unroll
        for (int mt = 0; mt < 4; ++mt) {
            const f32x4 vv = o[qs][mt];
            const float4 st = {vv[0]*inv, vv[1]*inv, vv[2]*inv, vv[3]*inv};
            *(float4*)(op + mt * 16) = st;
        }
    }
}

// ---------------- fallback (round-1 kernel) if ws too small ----------------

#define KSTR 72
__global__ __launch_bounds__(256) void attn_fallback(
    const float* __restrict__ q, const float* __restrict__ k,
    const float* __restrict__ v, const int* __restrict__ mask,
    float* __restrict__ out)
{
    const int bh = blockIdx.x, qt = blockIdx.y;
    const int tid = threadIdx.x, wave = tid >> 6, lane = tid & 63;
    const int g = lane >> 4, ln = lane & 15;
    __shared__ __align__(16) __bf16 Kl[64 * KSTR];
    __shared__ __align__(16) __bf16 Vt[64 * KSTR];
    __shared__ __align__(16) __bf16 Pl[4][16 * KSTR];
    const int qrow_frag = qt * 64 + wave * 16 + ln;
    const float* qp = q + ((size_t)bh * T_SEQ + qrow_frag) * D_HEAD;
    bf16x8 qf[2];
#pragma unroll
    for (int kc = 0; kc < 2; ++kc) {
        const float4 f0 = *(const float4*)(qp + kc * 32 + g * 8);
        const float4 f1 = *(const float4*)(qp + kc * 32 + g * 8 + 4);
        qf[kc][0]=(__bf16)f0.x; qf[kc][1]=(__bf16)f0.y; qf[kc][2]=(__bf16)f0.z; qf[kc][3]=(__bf16)f0.w;
        qf[kc][4]=(__bf16)f1.x; qf[kc][5]=(__bf16)f1.y; qf[kc][6]=(__bf16)f1.z; qf[kc][7]=(__bf16)f1.w;
    }
    f32x4 o[4];
#pragma unroll
    for (int nt = 0; nt < 4; ++nt) o[nt] = (f32x4){0.f,0.f,0.f,0.f};
    float m_i[4], l_i[4];
#pragma unroll
    for (int r = 0; r < 4; ++r) { m_i[r] = -1e30f; l_i[r] = 0.f; }
    const float scale = 0.125f;
    const int q0 = qt * 64 + wave * 16 + g * 4;
    const int* mrow[4];
#pragma unroll
    for (int r = 0; r < 4; ++r) mrow[r] = mask + (size_t)(q0 + r) * T_SEQ + ln;
    const int krow = tid >> 2, kpart = tid & 3;
    const int vj0 = (tid & 31) * 2, vd0 = (tid >> 5) * 8;
    for (int kt = 0; kt < T_SEQ / 64; ++kt) {
        __syncthreads();
        {
            const float* kp = k + ((size_t)bh * T_SEQ + kt * 64 + krow) * D_HEAD + kpart * 16;
            const float4 a0 = *(const float4*)(kp);
            const float4 a1 = *(const float4*)(kp + 4);
            const float4 a2 = *(const float4*)(kp + 8);
            const float4 a3 = *(const float4*)(kp + 12);
            bf16x8 w0, w1;
            w0[0]=(__bf16)a0.x; w0[1]=(__bf16)a0.y; w0[2]=(__bf16)a0.z; w0[3]=(__bf16)a0.w;
            w0[4]=(__bf16)a1.x; w0[5]=(__bf16)a1.y; w0[6]=(__bf16)a1.z; w0[7]=(__bf16)a1.w;
            w1[0]=(__bf16)a2.x; w1[1]=(__bf16)a2.y; w1[2]=(__bf16)a2.z; w1[3]=(__bf16)a2.w;
            w1[4]=(__bf16)a3.x; w1[5]=(__bf16)a3.y; w1[6]=(__bf16)a3.z; w1[7]=(__bf16)a3.w;
            *(bf16x8*)(&Kl[krow * KSTR + kpart * 16])     = w0;
            *(bf16x8*)(&Kl[krow * KSTR + kpart * 16 + 8]) = w1;
        }
        {
            const float* vp = v + ((size_t)bh * T_SEQ + kt * 64 + vj0) * D_HEAD + vd0;
            const float4 r00 = *(const float4*)(vp);
            const float4 r01 = *(const float4*)(vp + 4);
            const float4 r10 = *(const float4*)(vp + D_HEAD);
            const float4 r11 = *(const float4*)(vp + D_HEAD + 4);
            float e0[8] = {r00.x,r00.y,r00.z,r00.w,r01.x,r01.y,r01.z,r01.w};
            float e1[8] = {r10.x,r10.y,r10.z,r10.w,r11.x,r11.y,r11.z,r11.w};
#pragma unroll
            for (int i = 0; i < 8; ++i) {
                bf16x2 pr = { (__bf16)e0[i], (__bf16)e1[i] };
                *(bf16x2*)(&Vt[(vd0 + i) * KSTR + vj0]) = pr;
            }
        }
        __syncthreads();
        f32x4 s[4];
#pragma unroll
        for (int nt = 0; nt < 4; ++nt) {
            const bf16x8 kf0 = *(const bf16x8*)(&Kl[(nt*16 + ln) * KSTR + g * 8]);
            const bf16x8 kf1 = *(const bf16x8*)(&Kl[(nt*16 + ln) * KSTR + 32 + g * 8]);
            f32x4 c = (f32x4){0.f,0.f,0.f,0.f};
            c = __builtin_amdgcn_mfma_f32_16x16x32_bf16(qf[0], kf0, c, 0,0,0);
            c = __builtin_amdgcn_mfma_f32_16x16x32_bf16(qf[1], kf1, c, 0,0,0);
            s[nt] = c;
        }
#pragma unroll
        for (int nt = 0; nt < 4; ++nt)
#pragma unroll
            for (int r = 0; r < 4; ++r) {
                const float sv = s[nt][r] * scale;
                s[nt][r] = mrow[r][kt * 64 + nt * 16] ? -1e30f : sv;
            }
        float tm[4];
#pragma unroll
        for (int r = 0; r < 4; ++r)
            tm[r] = fmaxf(fmaxf(s[0][r], s[1][r]), fmaxf(s[2][r], s[3][r]));
#pragma unroll
        for (int off = 1; off < 16; off <<= 1)
#pragma unroll
            for (int r = 0; r < 4; ++r) tm[r] = fmaxf(tm[r], __shfl_xor(tm[r], off, 64));
        float alpha[4];
#pragma unroll
        for (int r = 0; r < 4; ++r) {
            const float mn = fmaxf(m_i[r], tm[r]);
            alpha[r] = __expf(m_i[r] - mn);
            m_i[r] = mn;
        }
#pragma unroll
        for (int nt = 0; nt < 4; ++nt)
#pragma unroll
            for (int r = 0; r < 4; ++r) o[nt][r] *= alpha[r];
        float rs[4] = {0.f,0.f,0.f,0.f};
#pragma unroll
        for (int nt = 0; nt < 4; ++nt)
#pragma unroll
            for (int r = 0; r < 4; ++r) {
                const float sv = s[nt][r];
                const float p = (sv < -1e29f) ? 0.f : __expf(sv - m_i[r]);
                rs[r] += p;
                Pl[wave][(g*4 + r) * KSTR + nt * 16 + ln] = (__bf16)p;
            }
#pragma unroll
        for (int off = 1; off < 16; off <<= 1)
#pragma unroll
            for (int r = 0; r < 4; ++r) rs[r] += __shfl_xor(rs[r], off, 64);
#pragma unroll
        for (int r = 0; r < 4; ++r) l_i[r] = l_i[r] * alpha[r] + rs[r];
        const bf16x8 pf0 = *(const bf16x8*)(&Pl[wave][ln * KSTR + g * 8]);
        const bf16x8 pf1 = *(const bf16x8*)(&Pl[wave][ln * KSTR + 32 + g * 8]);
#pragma unroll
        for (int nt = 0; nt < 4; ++nt) {
            const bf16x8 vf0 = *(const bf16x8*)(&Vt[(nt*16 + ln) * KSTR + g * 8]);
            const bf16x8 vf1 = *(const bf16x8*)(&Vt[(nt*16 + ln) * KSTR + 32 + g * 8]);
            o[nt] = __builtin_amdgcn_mfma_f32_16x16x32_bf16(pf0, vf0, o[nt], 0,0,0);
            o[nt] = __builtin_amdgcn_mfma_f32_16x16x32_bf16(pf1, vf1, o[nt], 0,0,0);
        }
    }
#pragma unroll
    for (int r = 0; r < 4; ++r) {
        const float inv = (l_i[r] > 0.f) ? (1.0f / l_i[r]) : 0.f;
        float* op = out + ((size_t)bh * T_SEQ + q0 + r) * D_HEAD + ln;
#pragma unroll
        for (int nt = 0; nt < 4; ++nt) op[nt * 16] = o[nt][r] * inv;
    }
}

extern "C" void kernel_launch(void* const* d_in, const int* in_sizes, int n_in,
                              void* d_out, int out_size, void* d_ws, size_t ws_size,
                              hipStream_t stream) {
    const float* q    = (const float*)d_in[0];
    const float* k    = (const float*)d_in[1];
    const float* v    = (const float*)d_in[2];
    const int*   mask = (const int*)d_in[3];
    float*       out  = (float*)d_out;

    if (ws_size >= WS_NEED) {
        __bf16* kbf = (__bf16*)((char*)d_ws + WS_KBF);
        __bf16* vtb = (__bf16*)((char*)d_ws + WS_VTB);
        unsigned long long* mbw = (unsigned long long*)((char*)d_ws + WS_MB);
        // pre-pass: K -> bf16; V -> bf16 transposed; mask -> bitwords
        cvt_k<<<(BH_N * T_SEQ * D_HEAD) / (256 * 8), 256, 0, stream>>>(k, kbf);
        vtrans<<<dim3(T_SEQ / 64, BH_N), 256, 0, stream>>>(v, vtb);
        mpack<<<(T_SEQ * T_SEQ) / 256, 256, 0, stream>>>(mask, mbw);
        attn_main<<<dim3(T_SEQ / TQ, BH_N), 256, 0, stream>>>(q, kbf, vtb, mbw, out);
    } else {
        attn_fallback<<<dim3(BH_N, T_SEQ / 64), 256, 0, stream>>>(q, k, v, mask, out);
    }
}